// Round 4
// baseline (2177.223 us; speedup 1.0000x reference)
//
#include <hip/hip_runtime.h>

// BailingMoeV2 grouped experts: y = combine(down(silu(gate(x))*up(x)))
// B=4 S=4096 H=2048 I=1024 E=32 K=4. All GEMMs via bf16 MFMA, fp32 accum.
//
// Structure: expert-sort assignments -> fp32->bf16 convert -> grouped GEMM
// (128x128x64 tiles, global_load_lds width-16, m97-class 2-barrier loop).
// k_gateup fuses gate+up (shared A staging, 64 MFMA/K-step/wave).
// k_down scales by routing weight and atomically combines into y.
// Workspace requirement: ~449 MiB.

#define NTOK    16384
#define HDIM    2048
#define IDIM    1024
#define EXPERTS 32
#define TOPK    4
#define NK      (NTOK*TOPK)
#define BM      128
#define BN      128
#define BK      64
#define MAX_TILES 544   // sum_e ceil(n_e/BM) <= NK/BM + EXPERTS

typedef __attribute__((ext_vector_type(8))) __bf16 bf16x8;
typedef __attribute__((ext_vector_type(4))) float  f32x4;

#define STAGE16(gp, lp) __builtin_amdgcn_global_load_lds( \
    (const __attribute__((address_space(1))) void*)(gp),  \
    (__attribute__((address_space(3))) void*)(lp), 16, 0, 0)

static __device__ __forceinline__ unsigned int f2bf(float f) {
  union { float f; unsigned int u; } v; v.f = f;
  return (v.u + 0x7FFFu + ((v.u >> 16) & 1u)) >> 16;   // RNE, finite inputs
}

// ---------------- setup kernels ----------------

__global__ void k_hist(const int* __restrict__ idx, int* __restrict__ counts) {
  __shared__ int lc[EXPERTS];
  const int t = threadIdx.x;
  if (t < EXPERTS) lc[t] = 0;
  __syncthreads();
  const int i = blockIdx.x * blockDim.x + t;
  if (i < NK) atomicAdd(&lc[idx[i]], 1);
  __syncthreads();
  if (t < EXPERTS && lc[t]) atomicAdd(&counts[t], lc[t]);
}

__global__ void k_scan(const int* __restrict__ counts, int* __restrict__ offsets,
                       int* __restrict__ tile_expert, int* __restrict__ tile_row0,
                       int* __restrict__ ntiles) {
  if (threadIdx.x == 0 && blockIdx.x == 0) {
    int off = 0, tcount = 0;
    for (int e = 0; e < EXPERTS; ++e) {
      offsets[e] = off;
      const int c = counts[e];
      for (int r = 0; r < c; r += BM) { tile_expert[tcount] = e; tile_row0[tcount] = off + r; ++tcount; }
      off += c;
    }
    offsets[EXPERTS] = off;
    *ntiles = tcount;
  }
}

__global__ void k_scatter(const int* __restrict__ idx, const float* __restrict__ wts,
                          const int* __restrict__ offsets, int* __restrict__ cursors,
                          int* __restrict__ tok_sorted, float* __restrict__ w_sorted) {
  __shared__ int lc[EXPERTS];
  __shared__ int lbase[EXPERTS];
  const int t = threadIdx.x;
  if (t < EXPERTS) lc[t] = 0;
  __syncthreads();
  const int i = blockIdx.x * blockDim.x + t;
  int e = 0, rank = 0;
  if (i < NK) { e = idx[i]; rank = atomicAdd(&lc[e], 1); }
  __syncthreads();
  if (t < EXPERTS) lbase[t] = lc[t] ? atomicAdd(&cursors[t], lc[t]) : 0;
  __syncthreads();
  if (i < NK) {
    const int p = offsets[e] + lbase[e] + rank;
    tok_sorted[p] = i >> 2;      // TOPK = 4
    w_sorted[p]   = wts[i];
  }
}

// fp32 -> bf16, 8 elems/thread, grid-stride
__global__ void k_cvt(const float4* __restrict__ in, uint4* __restrict__ out, int n8) {
  const int stride = gridDim.x * blockDim.x;
  for (int i = blockIdx.x * blockDim.x + threadIdx.x; i < n8; i += stride) {
    const float4 a = in[2*i], b = in[2*i+1];
    uint4 o;
    o.x = f2bf(a.x) | (f2bf(a.y) << 16);
    o.y = f2bf(a.z) | (f2bf(a.w) << 16);
    o.z = f2bf(b.x) | (f2bf(b.y) << 16);
    o.w = f2bf(b.z) | (f2bf(b.w) << 16);
    out[i] = o;
  }
}

// ---------------- GEMM 1+2: hmid = silu(xs @ gateW^T) * (xs @ upW^T) ----------------
// A = gathered x rows (bf16), B = gate/up weights [I][H] (native B^T layout, k-contig)
__global__ __launch_bounds__(256, 2) void k_gateup(
    const unsigned short* __restrict__ xbf,
    const unsigned short* __restrict__ gw,
    const unsigned short* __restrict__ uw,
    unsigned short* __restrict__ hmid,
    const int* __restrict__ tok_sorted,
    const int* __restrict__ offsets,
    const int* __restrict__ tile_expert,
    const int* __restrict__ tile_row0,
    const int* __restrict__ ntiles)
{
  if ((int)blockIdx.x >= *ntiles) return;
  const int e    = tile_expert[blockIdx.x];
  const int row0 = tile_row0[blockIdx.x];
  int mrows = offsets[e+1] - row0; if (mrows > BM) mrows = BM;
  const int ntile = blockIdx.y;

  __shared__ __align__(16) unsigned short lA [BM*BK];
  __shared__ __align__(16) unsigned short lBg[BN*BK];
  __shared__ __align__(16) unsigned short lBu[BN*BK];

  const int t = threadIdx.x, wid = t >> 6, lane = t & 63;
  const int wm = wid >> 1, wn = wid & 1;

  // per-lane global staging bases: unit u=(wid*4+c)*64+lane -> row u>>3, 16B slot u&7
  // (LDS dest is wave-uniform base + lane*16 -> linear layout matches r,cs exactly)
  const unsigned short* gA[4]; const unsigned short* gBg[4]; const unsigned short* gBu[4];
#pragma unroll
  for (int c = 0; c < 4; ++c) {
    const int u = (wid*4 + c)*64 + lane;
    const int r = u >> 3, cs = u & 7;
    const int ra = (r < mrows) ? r : (mrows - 1);           // clamp tail rows
    gA[c]  = xbf + (long)tok_sorted[row0 + ra]*HDIM + cs*8; // gathered token row
    const long wrow = (long)e*IDIM + ntile*BN + r;
    gBg[c] = gw + wrow*HDIM + cs*8;
    gBu[c] = uw + wrow*HDIM + cs*8;
  }

  f32x4 accg[4][4], accu[4][4];
#pragma unroll
  for (int i = 0; i < 4; ++i)
#pragma unroll
    for (int j = 0; j < 4; ++j) { accg[i][j] = (f32x4){0.f,0.f,0.f,0.f}; accu[i][j] = (f32x4){0.f,0.f,0.f,0.f}; }

  for (int kt = 0; kt < HDIM/BK; ++kt) {
#pragma unroll
    for (int c = 0; c < 4; ++c) {
      const int lo = (wid*4 + c) << 10;
      STAGE16(gA[c]  + kt*BK, (char*)lA  + lo);
      STAGE16(gBg[c] + kt*BK, (char*)lBg + lo);
      STAGE16(gBu[c] + kt*BK, (char*)lBu + lo);
    }
    __syncthreads();
#pragma unroll
    for (int kk = 0; kk < 2; ++kk) {
      const int ko = kk*32 + (lane >> 4)*8;
      bf16x8 af[4], bg[4], bu[4];
#pragma unroll
      for (int mi = 0; mi < 4; ++mi)
        af[mi] = *reinterpret_cast<const bf16x8*>(&lA[(wm*64 + mi*16 + (lane&15))*BK + ko]);
#pragma unroll
      for (int ni = 0; ni < 4; ++ni) {
        bg[ni] = *reinterpret_cast<const bf16x8*>(&lBg[(wn*64 + ni*16 + (lane&15))*BK + ko]);
        bu[ni] = *reinterpret_cast<const bf16x8*>(&lBu[(wn*64 + ni*16 + (lane&15))*BK + ko]);
      }
#pragma unroll
      for (int mi = 0; mi < 4; ++mi)
#pragma unroll
        for (int ni = 0; ni < 4; ++ni) {
          accg[mi][ni] = __builtin_amdgcn_mfma_f32_16x16x32_bf16(af[mi], bg[ni], accg[mi][ni], 0, 0, 0);
          accu[mi][ni] = __builtin_amdgcn_mfma_f32_16x16x32_bf16(af[mi], bu[ni], accu[mi][ni], 0, 0, 0);
        }
    }
    __syncthreads();
  }

  // epilogue: silu(g)*u -> bf16 hmid. C layout: col=lane&15, row=(lane>>4)*4+q
#pragma unroll
  for (int mi = 0; mi < 4; ++mi) {
    const int rbase = wm*64 + mi*16 + ((lane >> 4) << 2);
#pragma unroll
    for (int q = 0; q < 4; ++q) {
      const int r = rbase + q;
      if (r < mrows) {
        unsigned short* hrow = hmid + (long)(row0 + r)*IDIM + ntile*BN + wn*64 + (lane & 15);
#pragma unroll
        for (int ni = 0; ni < 4; ++ni) {
          const float g = accg[mi][ni][q], u = accu[mi][ni][q];
          const float s = g / (1.f + __expf(-g));
          hrow[ni*16] = (unsigned short)f2bf(s * u);
        }
      }
    }
  }
}

// ---------------- GEMM 3: y[tok] += w * (hmid @ downW^T) ----------------
__global__ __launch_bounds__(256, 3) void k_down(
    const unsigned short* __restrict__ hmid,
    const unsigned short* __restrict__ dw,
    float* __restrict__ y,
    const int* __restrict__ tok_sorted,
    const float* __restrict__ w_sorted,
    const int* __restrict__ offsets,
    const int* __restrict__ tile_expert,
    const int* __restrict__ tile_row0,
    const int* __restrict__ ntiles)
{
  if ((int)blockIdx.x >= *ntiles) return;
  const int e    = tile_expert[blockIdx.x];
  const int row0 = tile_row0[blockIdx.x];
  int mrows = offsets[e+1] - row0; if (mrows > BM) mrows = BM;
  const int ntile = blockIdx.y;

  __shared__ __align__(16) unsigned short lA[BM*BK];
  __shared__ __align__(16) unsigned short lB[BN*BK];

  const int t = threadIdx.x, wid = t >> 6, lane = t & 63;
  const int wm = wid >> 1, wn = wid & 1;

  const unsigned short* gA[4]; const unsigned short* gB[4];
#pragma unroll
  for (int c = 0; c < 4; ++c) {
    const int u = (wid*4 + c)*64 + lane;
    const int r = u >> 3, cs = u & 7;
    const int ra = (r < mrows) ? r : (mrows - 1);
    gA[c] = hmid + (long)(row0 + ra)*IDIM + cs*8;           // sorted rows: contiguous
    gB[c] = dw + ((long)e*HDIM + ntile*BN + r)*IDIM + cs*8;
  }

  f32x4 acc[4][4];
#pragma unroll
  for (int i = 0; i < 4; ++i)
#pragma unroll
    for (int j = 0; j < 4; ++j) acc[i][j] = (f32x4){0.f,0.f,0.f,0.f};

  for (int kt = 0; kt < IDIM/BK; ++kt) {
#pragma unroll
    for (int c = 0; c < 4; ++c) {
      const int lo = (wid*4 + c) << 10;
      STAGE16(gA[c] + kt*BK, (char*)lA + lo);
      STAGE16(gB[c] + kt*BK, (char*)lB + lo);
    }
    __syncthreads();
#pragma unroll
    for (int kk = 0; kk < 2; ++kk) {
      const int ko = kk*32 + (lane >> 4)*8;
      bf16x8 af[4], bf[4];
#pragma unroll
      for (int mi = 0; mi < 4; ++mi)
        af[mi] = *reinterpret_cast<const bf16x8*>(&lA[(wm*64 + mi*16 + (lane&15))*BK + ko]);
#pragma unroll
      for (int ni = 0; ni < 4; ++ni)
        bf[ni] = *reinterpret_cast<const bf16x8*>(&lB[(wn*64 + ni*16 + (lane&15))*BK + ko]);
#pragma unroll
      for (int mi = 0; mi < 4; ++mi)
#pragma unroll
        for (int ni = 0; ni < 4; ++ni)
          acc[mi][ni] = __builtin_amdgcn_mfma_f32_16x16x32_bf16(af[mi], bf[ni], acc[mi][ni], 0, 0, 0);
    }
    __syncthreads();
  }

  // epilogue: scale by routing weight, atomic combine into y (TOPK contributions/token)
#pragma unroll
  for (int mi = 0; mi < 4; ++mi) {
    const int rbase = wm*64 + mi*16 + ((lane >> 4) << 2);
#pragma unroll
    for (int q = 0; q < 4; ++q) {
      const int r = rbase + q;
      if (r < mrows) {
        const int p = row0 + r;
        const float wgt = w_sorted[p];
        float* yrow = y + (long)tok_sorted[p]*HDIM + ntile*BN + wn*64 + (lane & 15);
#pragma unroll
        for (int ni = 0; ni < 4; ++ni)
          atomicAdd(&yrow[ni*16], acc[mi][ni][q] * wgt);
      }
    }
  }
}

// ---------------- launch ----------------

extern "C" void kernel_launch(void* const* d_in, const int* in_sizes, int n_in,
                              void* d_out, int out_size, void* d_ws, size_t ws_size,
                              hipStream_t stream) {
  const float* hs  = (const float*)d_in[0];
  const float* gwf = (const float*)d_in[1];
  const float* uwf = (const float*)d_in[2];
  const float* dwf = (const float*)d_in[3];
  const int*   tix = (const int*)  d_in[4];
  const float* twf = (const float*)d_in[5];
  float* y = (float*)d_out;
  char* ws = (char*)d_ws;

  // workspace layout (needs ~449 MiB)
  int*   counts      = (int*)  (ws + 0);       // 32
  int*   offsets     = (int*)  (ws + 256);     // 33
  int*   cursors     = (int*)  (ws + 512);     // 32
  int*   ntiles      = (int*)  (ws + 768);     // 1
  int*   tile_expert = (int*)  (ws + 1024);    // 544
  int*   tile_row0   = (int*)  (ws + 4096);    // 544
  int*   tok_sorted  = (int*)  (ws + 8192);    // 65536
  float* w_sorted    = (float*)(ws + 8192 + 262144);
  char* big = ws + (1 << 20);
  unsigned short* xbf  = (unsigned short*)big;                                  //  64 MiB
  unsigned short* wgb  = (unsigned short*)(big + 67108864LL);                   // 128 MiB (gate, then down)
  unsigned short* wub  = (unsigned short*)(big + 67108864LL + 134217728LL);     // 128 MiB
  unsigned short* hmid = (unsigned short*)(big + 67108864LL + 2*134217728LL);   // 128 MiB

  hipMemsetAsync(ws, 0, 1024, stream);                                  // counters
  hipMemsetAsync(d_out, 0, (size_t)NTOK*HDIM*sizeof(float), stream);    // y = 0 for atomics

  k_hist   <<<NK/256, 256, 0, stream>>>(tix, counts);
  k_scan   <<<1, 64, 0, stream>>>(counts, offsets, tile_expert, tile_row0, ntiles);
  k_scatter<<<NK/256, 256, 0, stream>>>(tix, twf, offsets, cursors, tok_sorted, w_sorted);

  k_cvt<<<4096, 256, 0, stream>>>((const float4*)hs,  (uint4*)xbf, NTOK*HDIM/8);
  k_cvt<<<4096, 256, 0, stream>>>((const float4*)gwf, (uint4*)wgb, EXPERTS*IDIM*HDIM/8);
  k_cvt<<<4096, 256, 0, stream>>>((const float4*)uwf, (uint4*)wub, EXPERTS*IDIM*HDIM/8);

  k_gateup<<<dim3(MAX_TILES, IDIM/BN), 256, 0, stream>>>(
      xbf, wgb, wub, hmid, tok_sorted, offsets, tile_expert, tile_row0, ntiles);

  // down weights reuse gate's bf16 buffer (stream-ordered after k_gateup reads it)
  k_cvt<<<4096, 256, 0, stream>>>((const float4*)dwf, (uint4*)wgb, EXPERTS*HDIM*IDIM/8);

  k_down<<<dim3(MAX_TILES, HDIM/BN), 256, 0, stream>>>(
      hmid, wgb, y, tok_sorted, w_sorted, offsets, tile_expert, tile_row0, ntiles);
}